// Round 1
// baseline (5121.945 us; speedup 1.0000x reference)
//
#include <hip/hip_runtime.h>
#include <hip/hip_bf16.h>
#include <math.h>

// Problem constants (fixed by the reference).
#define N_ROWS 16384
#define D_INN  360
#define HID    512
#define M_SLOTS 2048

// ---- monotone float<->uint mapping for atomicMax on floats ----
__device__ __forceinline__ unsigned fmap(float f){
  unsigned u = __float_as_uint(f);
  return (u & 0x80000000u) ? ~u : (u | 0x80000000u);
}
__device__ __forceinline__ float funmap(unsigned u){
  unsigned b = (u & 0x80000000u) ? (u ^ 0x80000000u) : ~u;
  return __uint_as_float(b);
}

// C[i,j] = relu(sum_k A[i,k]*W[j,k] + b[j]);  A:[n,K] row-major, W:[H,K] row-major.
// 64x64 tile, 256 threads, 4x4 per thread, K-tile 16.
__global__ __launch_bounds__(256) void gemm_relu(const float* __restrict__ A,
                                                 const float* __restrict__ W,
                                                 const float* __restrict__ b,
                                                 float* __restrict__ C,
                                                 int n, int K, int H)
{
  __shared__ float As[16][68]; // [kk][row], stride 68 floats -> 16B-aligned float4 rows
  __shared__ float Ws[16][68]; // [kk][col]
  const int t  = threadIdx.x;
  const int tx = t & 15, ty = t >> 4;
  const int rowBase = blockIdx.y * 64, colBase = blockIdx.x * 64;
  float acc[4][4] = {};
  for (int k0 = 0; k0 < K; k0 += 16){
    const int kk = t & 15;
    const int rr = t >> 4;
#pragma unroll
    for (int p = 0; p < 4; ++p){
      int r  = rr + p*16;
      int gk = k0 + kk;
      float av = 0.f, wv = 0.f;
      if (gk < K){
        av = A[(size_t)(rowBase + r) * K + gk];
        wv = W[(size_t)(colBase + r) * K + gk];
      }
      As[kk][r] = av;
      Ws[kk][r] = wv;
    }
    __syncthreads();
#pragma unroll
    for (int kq = 0; kq < 16; ++kq){
      float4 a4 = *(const float4*)&As[kq][ty*4];
      float4 w4 = *(const float4*)&Ws[kq][tx*4];
      float a[4] = {a4.x, a4.y, a4.z, a4.w};
      float w[4] = {w4.x, w4.y, w4.z, w4.w};
#pragma unroll
      for (int i = 0; i < 4; ++i)
#pragma unroll
        for (int j = 0; j < 4; ++j)
          acc[i][j] += a[i] * w[j];
    }
    __syncthreads();
  }
#pragma unroll
  for (int i = 0; i < 4; ++i){
    int r = rowBase + ty*4 + i;
#pragma unroll
    for (int j = 0; j < 4; ++j){
      int c = colBase + tx*4 + j;
      float v = acc[i][j] + b[c];
      C[(size_t)r * H + c] = v > 0.f ? v : 0.f;
    }
  }
}

// Pass over S = Q K^T computing per-row: max (=S[i,g_i]), argmax g_i, 1/sum(exp(S-max)),
// max(-S), 1/sum(exp(-S-max(-S))); and per-column max of S via atomicMax.
// Block = 16 Q-rows; thread (rA=t>>4, cA=t&15) owns one S element per 16-col tile.
__global__ __launch_bounds__(256) void stats_kernel(const float* __restrict__ Q,
                                                    const float* __restrict__ Km,
                                                    float* __restrict__ rowm, float* __restrict__ rsp,
                                                    float* __restrict__ rmn,  float* __restrict__ rsn,
                                                    int* __restrict__ gidx,   unsigned* __restrict__ colmaxU)
{
  __shared__ float Ks[16][516];   // K tile rows, padded stride (16B aligned, +4 banks)
  __shared__ float Ss[16][17];    // S tile for column scan
  const int t  = threadIdx.x;
  const int rA = t >> 4, cA = t & 15;
  const int bR = blockIdx.x * 16;
  const float* qrow = Q + (size_t)(bR + rA) * HID;

  float m_run = -INFINITY, s_run = 0.f;
  float mn_run = -INFINITY, sn_run = 0.f;
  float bv = -INFINITY; int bj = 0;

  for (int mt = 0; mt < M_SLOTS/16; ++mt){
#pragma unroll
    for (int p = 0; p < 8; ++p){
      int fi = (p*256 + t) * 4;
      int c = fi >> 9, k = fi & 511;
      *(float4*)&Ks[c][k] = *(const float4*)&Km[(size_t)(mt*16 + c)*HID + k];
    }
    __syncthreads();

    float acc = 0.f;
#pragma unroll 8
    for (int k = 0; k < HID; k += 4){
      float4 q4 = *(const float4*)&qrow[k];
      float4 k4 = *(const float4*)&Ks[cA][k];
      acc += q4.x*k4.x + q4.y*k4.y + q4.z*k4.z + q4.w*k4.w;
    }

    // butterfly over the 16 lanes of this row: (max, first-argmax) and min
    float tv = acc; int tj = mt*16 + cA; float tmin = acc;
#pragma unroll
    for (int d = 1; d < 16; d <<= 1){
      float ov = __shfl_xor(tv, d);
      int   oj = __shfl_xor(tj, d);
      float om = __shfl_xor(tmin, d);
      if (ov > tv || (ov == tv && oj < tj)){ tv = ov; tj = oj; }
      tmin = fminf(tmin, om);
    }
    float sp = __expf(acc - tv);     // exp(S - tilemax)
    float sn = __expf(tmin - acc);   // exp(-S - (-tilemin))
#pragma unroll
    for (int d = 1; d < 16; d <<= 1){
      sp += __shfl_xor(sp, d);
      sn += __shfl_xor(sn, d);
    }
    // online merge (all 16 lanes redundantly hold identical running stats)
    {
      float nm = fmaxf(m_run, tv);
      s_run = s_run * __expf(m_run - nm) + sp * __expf(tv - nm);
      m_run = nm;
      float tmn = -tmin;
      float nmn = fmaxf(mn_run, tmn);
      sn_run = sn_run * __expf(mn_run - nmn) + sn * __expf(tmn - nmn);
      mn_run = nmn;
      if (tv > bv){ bv = tv; bj = tj; }   // strict > keeps earliest (first-index ties)
    }
    // column max over this block's 16 rows
    Ss[rA][cA] = acc;
    __syncthreads();
    if (t < 16){
      float cm = Ss[0][t];
#pragma unroll
      for (int r = 1; r < 16; ++r) cm = fmaxf(cm, Ss[r][t]);
      atomicMax(&colmaxU[mt*16 + t], fmap(cm));
    }
    __syncthreads();
  }
  if (cA == 0){
    int row = bR + rA;
    rowm[row] = m_run;          // == S[row, g_row]
    rsp[row]  = 1.f / s_run;
    rmn[row]  = mn_run;
    rsn[row]  = 1.f / sn_run;
    gidx[row] = bj;
  }
}

// Recompute S tiles, turn into softmax weights (both signs), accumulate P = sm@K and
// Pn = smN@K over M, write pred_min_p = Q*P, pred_min_n = Q*Pn.
// Block = 16 Q-rows. Phase A: 1 S elem/thread. Phase B: wave w owns rows w*4..+3,
// lane owns 8 consecutive h columns (h0 = lane*8).
__global__ __launch_bounds__(256) void pv_kernel(const float* __restrict__ Q,
                                                 const float* __restrict__ Km,
                                                 const float* __restrict__ rowm, const float* __restrict__ rsp,
                                                 const float* __restrict__ rmn,  const float* __restrict__ rsn,
                                                 float* __restrict__ outP, float* __restrict__ outN)
{
  __shared__ float Ks[16][516];
  __shared__ float Wpc[16][20];   // [c][r], stride 20 -> aligned float4 at r0 in {0,4,8,12}
  __shared__ float Wnc[16][20];
  const int t  = threadIdx.x;
  const int rA = t >> 4, cA = t & 15;
  const int bR = blockIdx.x * 16;
  const int w  = t >> 6, lane = t & 63;
  const int r0 = w * 4;
  const int h0 = lane * 8;
  const float* qrow = Q + (size_t)(bR + rA) * HID;
  const float mp = rowm[bR + rA], isp = rsp[bR + rA];
  const float mn = rmn[bR + rA],  isn = rsn[bR + rA];

  float accp[4][8] = {};
  float accn[4][8] = {};

  for (int mt = 0; mt < M_SLOTS/16; ++mt){
#pragma unroll
    for (int p = 0; p < 8; ++p){
      int fi = (p*256 + t) * 4;
      int c = fi >> 9, k = fi & 511;
      *(float4*)&Ks[c][k] = *(const float4*)&Km[(size_t)(mt*16 + c)*HID + k];
    }
    __syncthreads();

    float s = 0.f;
#pragma unroll 8
    for (int k = 0; k < HID; k += 4){
      float4 q4 = *(const float4*)&qrow[k];
      float4 k4 = *(const float4*)&Ks[cA][k];
      s += q4.x*k4.x + q4.y*k4.y + q4.z*k4.z + q4.w*k4.w;
    }
    Wpc[cA][rA] = __expf(s - mp) * isp;    // smP[row, col]
    Wnc[cA][rA] = __expf(-s - mn) * isn;   // smN[row, col]
    __syncthreads();

#pragma unroll
    for (int c = 0; c < 16; ++c){
      float4 kv0 = *(const float4*)&Ks[c][h0];
      float4 kv1 = *(const float4*)&Ks[c][h0 + 4];
      float4 wp4 = *(const float4*)&Wpc[c][r0];
      float4 wn4 = *(const float4*)&Wnc[c][r0];
      float wp[4] = {wp4.x, wp4.y, wp4.z, wp4.w};
      float wn[4] = {wn4.x, wn4.y, wn4.z, wn4.w};
#pragma unroll
      for (int r = 0; r < 4; ++r){
        accp[r][0] += wp[r]*kv0.x; accp[r][1] += wp[r]*kv0.y;
        accp[r][2] += wp[r]*kv0.z; accp[r][3] += wp[r]*kv0.w;
        accp[r][4] += wp[r]*kv1.x; accp[r][5] += wp[r]*kv1.y;
        accp[r][6] += wp[r]*kv1.z; accp[r][7] += wp[r]*kv1.w;
        accn[r][0] += wn[r]*kv0.x; accn[r][1] += wn[r]*kv0.y;
        accn[r][2] += wn[r]*kv0.z; accn[r][3] += wn[r]*kv0.w;
        accn[r][4] += wn[r]*kv1.x; accn[r][5] += wn[r]*kv1.y;
        accn[r][6] += wn[r]*kv1.z; accn[r][7] += wn[r]*kv1.w;
      }
    }
    __syncthreads();
  }

#pragma unroll
  for (int r = 0; r < 4; ++r){
    size_t row = (size_t)(bR + r0 + r);
    const float* q = &Q[row*HID + h0];
    float4 q0 = *(const float4*)&q[0];
    float4 q1 = *(const float4*)&q[4];
    float4 o0, o1;
    o0.x = q0.x*accp[r][0]; o0.y = q0.y*accp[r][1]; o0.z = q0.z*accp[r][2]; o0.w = q0.w*accp[r][3];
    o1.x = q1.x*accp[r][4]; o1.y = q1.y*accp[r][5]; o1.z = q1.z*accp[r][6]; o1.w = q1.w*accp[r][7];
    *(float4*)&outP[row*HID + h0]     = o0;
    *(float4*)&outP[row*HID + h0 + 4] = o1;
    o0.x = q0.x*accn[r][0]; o0.y = q0.y*accn[r][1]; o0.z = q0.z*accn[r][2]; o0.w = q0.w*accn[r][3];
    o1.x = q1.x*accn[r][4]; o1.y = q1.y*accn[r][5]; o1.z = q1.z*accn[r][6]; o1.w = q1.w*accn[r][7];
    *(float4*)&outN[row*HID + h0]     = o0;
    *(float4*)&outN[row*HID + h0 + 4] = o1;
  }
}

// One block per memory slot m: gather rows with g_i==m, accumulate w_i*Q_i, add K row,
// L2-normalize. w_i = exp(rowm[i] - colmax[m]). If train==0, mem = K unchanged.
__global__ __launch_bounds__(256) void upload_kernel(const float* __restrict__ Q,
                                                     const float* __restrict__ Km,
                                                     const float* __restrict__ rowm,
                                                     const int* __restrict__ gidx,
                                                     const unsigned* __restrict__ colmaxU,
                                                     const int* __restrict__ train,
                                                     float* __restrict__ mem)
{
  const int m = blockIdx.x, t = threadIdx.x;
  const int h0 = t * 2;
  float2 kv = *(const float2*)&Km[(size_t)m*HID + h0];
  if (*train == 0){
    mem[(size_t)m*HID + h0]     = kv.x;
    mem[(size_t)m*HID + h0 + 1] = kv.y;
    return;
  }
  const float cmax = funmap(colmaxU[m]);
  float a0 = 0.f, a1 = 0.f;
  __shared__ int cnt;
  __shared__ int   lidx[256];
  __shared__ float lw[256];
  for (int base = 0; base < N_ROWS; base += 256){
    if (t == 0) cnt = 0;
    __syncthreads();
    int i = base + t;
    if (gidx[i] == m){
      int p = atomicAdd(&cnt, 1);
      lidx[p] = i;
      lw[p]   = __expf(rowm[i] - cmax);
    }
    __syncthreads();
    int c = cnt;
    for (int k = 0; k < c; ++k){
      float wv = lw[k];
      const float* q = &Q[(size_t)lidx[k]*HID + h0];
      a0 += wv * q[0];
      a1 += wv * q[1];
    }
    __syncthreads();
  }
  float v0 = a0 + kv.x, v1 = a1 + kv.y;
  __shared__ float red[256];
  red[t] = v0*v0 + v1*v1;
  __syncthreads();
  for (int s = 128; s > 0; s >>= 1){
    if (t < s) red[t] += red[t + s];
    __syncthreads();
  }
  float nrm = sqrtf(red[0]);
  float rinv = 1.f / fmaxf(nrm, 1e-12f);
  mem[(size_t)m*HID + h0]     = v0 * rinv;
  mem[(size_t)m*HID + h0 + 1] = v1 * rinv;
}

// pred[i] = sum_h Q[i,h]*Wd[h] + bd ; one wave per row.
__global__ __launch_bounds__(256) void pred_kernel(const float* __restrict__ Q,
                                                   const float* __restrict__ Wd,
                                                   const float* __restrict__ bd,
                                                   float* __restrict__ pred)
{
  const int w = threadIdx.x >> 6, lane = threadIdx.x & 63;
  const int row = blockIdx.x * 4 + w;
  const float* q = &Q[(size_t)row * HID];
  float p = 0.f;
#pragma unroll
  for (int j = 0; j < 8; ++j){
    int h = lane + 64*j;
    p += q[h] * Wd[h];
  }
#pragma unroll
  for (int d = 32; d > 0; d >>= 1) p += __shfl_down(p, d);
  if (lane == 0) pred[row] = p + bd[0];
}

extern "C" void kernel_launch(void* const* d_in, const int* in_sizes, int n_in,
                              void* d_out, int out_size, void* d_ws, size_t ws_size,
                              hipStream_t stream)
{
  const float* x   = (const float*)d_in[0];
  const float* Km  = (const float*)d_in[1];
  const float* W1  = (const float*)d_in[2];
  const float* b1  = (const float*)d_in[3];
  const float* W2  = (const float*)d_in[4];
  const float* b2  = (const float*)d_in[5];
  const float* W3  = (const float*)d_in[6];
  const float* b3  = (const float*)d_in[7];
  const float* Wd  = (const float*)d_in[8];
  const float* bd  = (const float*)d_in[9];
  const int* train = (const int*)d_in[10];

  float* out  = (float*)d_out;
  float* pred = out;                           // [16384]
  float* outN = out + 16384;                   // pred_min_n [16384,512]
  float* outP = out + 16384 + 8388608;         // pred_min_p [16384,512]
  float* memo = out + 16384 + 2*8388608;       // mem [2048,512]

  char* ws = (char*)d_ws;
  float*    Q       = (float*)ws;                          // 33,554,432 B
  float*    rowm    = (float*)(ws + 33554432);             // 64 KB each
  float*    rsp     = (float*)(ws + 33619968);
  float*    rmn     = (float*)(ws + 33685504);
  float*    rsn     = (float*)(ws + 33751040);
  int*      gidx    = (int*)  (ws + 33816576);
  unsigned* colmaxU = (unsigned*)(ws + 33882112);          // 8 KB

  // h1/h2 scratch live in output regions that are dead until pv_kernel overwrites them.
  float* h1 = outN;
  float* h2 = outP;

  hipMemsetAsync(colmaxU, 0, M_SLOTS*sizeof(unsigned), stream);  // mapped -inf

  dim3 blk(256);
  gemm_relu<<<dim3(HID/64, N_ROWS/64), blk, 0, stream>>>(x,  W1, b1, h1, N_ROWS, D_INN, HID);
  gemm_relu<<<dim3(HID/64, N_ROWS/64), blk, 0, stream>>>(h1, W2, b2, h2, N_ROWS, HID,  HID);
  gemm_relu<<<dim3(HID/64, N_ROWS/64), blk, 0, stream>>>(h2, W3, b3, Q,  N_ROWS, HID,  HID);

  stats_kernel<<<N_ROWS/16, blk, 0, stream>>>(Q, Km, rowm, rsp, rmn, rsn, gidx, colmaxU);
  pv_kernel  <<<N_ROWS/16, blk, 0, stream>>>(Q, Km, rowm, rsp, rmn, rsn, outP, outN);
  upload_kernel<<<M_SLOTS, blk, 0, stream>>>(Q, Km, rowm, gidx, colmaxU, train, memo);
  pred_kernel<<<N_ROWS/4, blk, 0, stream>>>(Q, Wd, bd, pred);
}

// Round 2
// 982.245 us; speedup vs baseline: 5.2145x; 5.2145x over previous
//
#include <hip/hip_runtime.h>
#include <math.h>

// Problem constants (fixed by the reference).
#define N_ROWS 16384
#define D_INN  360
#define HID    512
#define M_SLOTS 2048

typedef __attribute__((ext_vector_type(8))) short short8v;
typedef __attribute__((ext_vector_type(4))) float f32x4;
typedef __attribute__((address_space(1))) unsigned int as1_uint;
typedef __attribute__((address_space(3))) unsigned int as3_uint;

// ---- bf16 helpers (manual, RNE) ----
__device__ __forceinline__ unsigned short bf16_rne(float f){
  unsigned u = __float_as_uint(f);
  unsigned r = u + 0x7FFFu + ((u >> 16) & 1u);
  return (unsigned short)(r >> 16);
}
__device__ __forceinline__ float bf16_to_f32(unsigned short h){
  return __uint_as_float(((unsigned)h) << 16);
}

__device__ __forceinline__ void glds16(const void* g, void* l){
  __builtin_amdgcn_global_load_lds((const as1_uint*)g, (as3_uint*)l, 16, 0, 0);
}

// ---- monotone float<->uint mapping for atomicMax on floats (fallback path) ----
__device__ __forceinline__ unsigned fmap(float f){
  unsigned u = __float_as_uint(f);
  return (u & 0x80000000u) ? ~u : (u | 0x80000000u);
}
__device__ __forceinline__ float funmap(unsigned u){
  unsigned b = (u & 0x80000000u) ? (u ^ 0x80000000u) : ~u;
  return __uint_as_float(b);
}

// ============================ shared (both paths) ============================

// C[i,j] = relu(sum_k A[i,k]*W[j,k] + b[j]);  A:[n,K] row-major, W:[H,K] row-major.
__global__ __launch_bounds__(256) void gemm_relu(const float* __restrict__ A,
                                                 const float* __restrict__ W,
                                                 const float* __restrict__ b,
                                                 float* __restrict__ C,
                                                 int n, int K, int H)
{
  __shared__ float As[16][68];
  __shared__ float Ws[16][68];
  const int t  = threadIdx.x;
  const int tx = t & 15, ty = t >> 4;
  const int rowBase = blockIdx.y * 64, colBase = blockIdx.x * 64;
  float acc[4][4] = {};
  for (int k0 = 0; k0 < K; k0 += 16){
    const int kk = t & 15;
    const int rr = t >> 4;
#pragma unroll
    for (int p = 0; p < 4; ++p){
      int r  = rr + p*16;
      int gk = k0 + kk;
      float av = 0.f, wv = 0.f;
      if (gk < K){
        av = A[(size_t)(rowBase + r) * K + gk];
        wv = W[(size_t)(colBase + r) * K + gk];
      }
      As[kk][r] = av;
      Ws[kk][r] = wv;
    }
    __syncthreads();
#pragma unroll
    for (int kq = 0; kq < 16; ++kq){
      float4 a4 = *(const float4*)&As[kq][ty*4];
      float4 w4 = *(const float4*)&Ws[kq][tx*4];
      float a[4] = {a4.x, a4.y, a4.z, a4.w};
      float w[4] = {w4.x, w4.y, w4.z, w4.w};
#pragma unroll
      for (int i = 0; i < 4; ++i)
#pragma unroll
        for (int j = 0; j < 4; ++j)
          acc[i][j] += a[i] * w[j];
    }
    __syncthreads();
  }
#pragma unroll
  for (int i = 0; i < 4; ++i){
    int r = rowBase + ty*4 + i;
#pragma unroll
    for (int j = 0; j < 4; ++j){
      int c = colBase + tx*4 + j;
      float v = acc[i][j] + b[c];
      C[(size_t)r * H + c] = v > 0.f ? v : 0.f;
    }
  }
}

// pred[i] = sum_h Q[i,h]*Wd[h] + bd ; one wave per row.
__global__ __launch_bounds__(256) void pred_kernel(const float* __restrict__ Q,
                                                   const float* __restrict__ Wd,
                                                   const float* __restrict__ bd,
                                                   float* __restrict__ pred)
{
  const int w = threadIdx.x >> 6, lane = threadIdx.x & 63;
  const int row = blockIdx.x * 4 + w;
  const float* q = &Q[(size_t)row * HID];
  float p = 0.f;
#pragma unroll
  for (int j = 0; j < 8; ++j){
    int h = lane + 64*j;
    p += q[h] * Wd[h];
  }
#pragma unroll
  for (int d = 32; d > 0; d >>= 1) p += __shfl_down(p, d);
  if (lane == 0) pred[row] = p + bd[0];
}

// ============================ MFMA path ============================

// split f32 -> bf16 hi + bf16 lo (residual)
__global__ __launch_bounds__(256) void cvt_split(const float* __restrict__ src,
                                                 unsigned short* __restrict__ hi,
                                                 unsigned short* __restrict__ lo,
                                                 int nelem)
{
  int idx = (blockIdx.x*256 + threadIdx.x) * 8;
  if (idx >= nelem) return;
  float4 a = *(const float4*)&src[idx];
  float4 b = *(const float4*)&src[idx+4];
  float v[8] = {a.x,a.y,a.z,a.w,b.x,b.y,b.z,b.w};
  short8v hv, lv;
#pragma unroll
  for (int e=0;e<8;++e){
    unsigned short h = bf16_rne(v[e]);
    float hf = bf16_to_f32(h);
    hv[e] = (short)h;
    lv[e] = (short)bf16_rne(v[e] - hf);
  }
  *(short8v*)&hi[idx] = hv;
  *(short8v*)&lo[idx] = lv;
}

// Kt[h][slot] = bf16(K[slot][h])  -- transposed bf16 copy of memory matrix
__global__ __launch_bounds__(256) void kt_kernel(const float* __restrict__ K,
                                                 unsigned short* __restrict__ Kt)
{
  __shared__ float tile[64][65];
  const int sb = blockIdx.x * 64;  // slot base
  const int hb = blockIdx.y * 64;  // h base
  const int t = threadIdx.x;
  {
    int r = t >> 2, cq = t & 3;
#pragma unroll
    for (int q=0;q<4;++q){
      float4 v = *(const float4*)&K[(size_t)(sb+r)*HID + hb + cq*16 + q*4];
      tile[r][cq*16+q*4+0]=v.x; tile[r][cq*16+q*4+1]=v.y;
      tile[r][cq*16+q*4+2]=v.z; tile[r][cq*16+q*4+3]=v.w;
    }
  }
  __syncthreads();
  {
    int hl = t >> 2, sq = t & 3;
    unsigned short w16[16];
#pragma unroll
    for (int q=0;q<16;++q) w16[q] = bf16_rne(tile[sq*16+q][hl]);
    *(uint4*)&Kt[(size_t)(hb+hl)*M_SLOTS + sb + sq*16]     = *(uint4*)&w16[0];
    *(uint4*)&Kt[(size_t)(hb+hl)*M_SLOTS + sb + sq*16 + 8] = *(uint4*)&w16[8];
  }
}

// S = Q K^T via 3-term split-bf16 MFMA (f32-grade accuracy).
// Tile: BM=64 (rows) x BN=128 (slots), BK=64. 4 waves: wave (w>>1) row-half, (w&1) col-half.
// Epilogue: write S bf16, per-(row, col-half-tile) stats partials, per-column tile max.
__global__ __launch_bounds__(256) void sgemm_stats(
    const unsigned short* __restrict__ Qhi, const unsigned short* __restrict__ Qlo,
    const unsigned short* __restrict__ Khi, const unsigned short* __restrict__ Klo,
    unsigned short* __restrict__ Sb,
    float* __restrict__ pmax, int* __restrict__ pcol,
    float* __restrict__ psum, float* __restrict__ pnmax, float* __restrict__ pnsum,
    float* __restrict__ pcolmax)
{
  __shared__ char smem[49152];
  unsigned short* Ah = (unsigned short*)smem;            // [64 rows][64 k] bf16, chunk-swizzled
  unsigned short* Al = (unsigned short*)(smem + 8192);
  unsigned short* Bh = (unsigned short*)(smem + 16384);  // [128 rows][64 k]
  unsigned short* Bl = (unsigned short*)(smem + 32768);
  const int t = threadIdx.x;
  const int lane = t & 63, w = t >> 6;
  const int l15 = lane & 15, l4 = lane >> 4;
  const int rb = blockIdx.x;      // 0..255 row block
  const int cb = blockIdx.y;      // 0..15  col block
  const int rowBase = rb * 64;
  const int colBase = cb * 128;
  const int wr = (w >> 1) * 32;
  const int wc = (w & 1) * 64;

  f32x4 acc[2][4];
#pragma unroll
  for (int i=0;i<2;++i)
#pragma unroll
    for (int j=0;j<4;++j) acc[i][j] = (f32x4){0.f,0.f,0.f,0.f};

  for (int kt = 0; kt < 8; ++kt){
    const int k0 = kt * 64;
    // stage: LDS chunk c holds global chunk (c ^ (r&7))  [pre-swizzled source]
#pragma unroll
    for (int p = 0; p < 2; ++p){
      int idx = p*256 + t;
      int r = idx >> 3, c = idx & 7;
      int cc = c ^ (r & 7);
      size_t go = (size_t)(rowBase + r) * HID + (k0 + cc*8);
      glds16(Qhi + go, (char*)Ah + idx*16);
      glds16(Qlo + go, (char*)Al + idx*16);
    }
#pragma unroll
    for (int p = 0; p < 4; ++p){
      int idx = p*256 + t;
      int r = idx >> 3, c = idx & 7;
      int cc = c ^ (r & 7);
      size_t go = (size_t)(colBase + r) * HID + (k0 + cc*8);
      glds16(Khi + go, (char*)Bh + idx*16);
      glds16(Klo + go, (char*)Bl + idx*16);
    }
    __syncthreads();

#pragma unroll
    for (int s = 0; s < 2; ++s){
      short8v a_h[2], a_l[2], b_h[4], b_l[4];
#pragma unroll
      for (int rt = 0; rt < 2; ++rt){
        int r = wr + rt*16 + l15;
        int off = r*128 + ((s*4 + l4) ^ (r & 7))*16;
        a_h[rt] = *(const short8v*)((const char*)Ah + off);
        a_l[rt] = *(const short8v*)((const char*)Al + off);
      }
#pragma unroll
      for (int ct = 0; ct < 4; ++ct){
        int r = wc + ct*16 + l15;
        int off = r*128 + ((s*4 + l4) ^ (r & 7))*16;
        b_h[ct] = *(const short8v*)((const char*)Bh + off);
        b_l[ct] = *(const short8v*)((const char*)Bl + off);
      }
#pragma unroll
      for (int rt = 0; rt < 2; ++rt)
#pragma unroll
        for (int ct = 0; ct < 4; ++ct){
          acc[rt][ct] = __builtin_amdgcn_mfma_f32_16x16x32_bf16(a_h[rt], b_h[ct], acc[rt][ct], 0,0,0);
          acc[rt][ct] = __builtin_amdgcn_mfma_f32_16x16x32_bf16(a_h[rt], b_l[ct], acc[rt][ct], 0,0,0);
          acc[rt][ct] = __builtin_amdgcn_mfma_f32_16x16x32_bf16(a_l[rt], b_h[ct], acc[rt][ct], 0,0,0);
        }
    }
    __syncthreads();
  }

  // ---- row stats (per wave over its 64-col half) ----
  // C layout: tile row = l4*4+reg, col = l15.
#pragma unroll
  for (int rt = 0; rt < 2; ++rt){
#pragma unroll
    for (int reg = 0; reg < 4; ++reg){
      float v0 = acc[rt][0][reg], v1 = acc[rt][1][reg];
      float v2 = acc[rt][2][reg], v3 = acc[rt][3][reg];
      float bvv = v0; int bcc = colBase + wc + l15;
      if (v1 > bvv){ bvv = v1; bcc = colBase + wc + 16 + l15; }
      if (v2 > bvv){ bvv = v2; bcc = colBase + wc + 32 + l15; }
      if (v3 > bvv){ bvv = v3; bcc = colBase + wc + 48 + l15; }
      float mnv = fminf(fminf(v0,v1), fminf(v2,v3));
#pragma unroll
      for (int d = 1; d < 16; d <<= 1){
        float ov = __shfl_xor(bvv, d);
        int   oc = __shfl_xor(bcc, d);
        float om = __shfl_xor(mnv, d);
        if (ov > bvv || (ov == bvv && oc < bcc)){ bvv = ov; bcc = oc; }
        mnv = fminf(mnv, om);
      }
      float sp = __expf(v0-bvv)+__expf(v1-bvv)+__expf(v2-bvv)+__expf(v3-bvv);
      float sn = __expf(mnv-v0)+__expf(mnv-v1)+__expf(mnv-v2)+__expf(mnv-v3);
#pragma unroll
      for (int d = 1; d < 16; d <<= 1){ sp += __shfl_xor(sp,d); sn += __shfl_xor(sn,d); }
      if (l15 == 0){
        int row = rowBase + wr + rt*16 + l4*4 + reg;
        size_t pi = (size_t)row*32 + cb*2 + (w & 1);
        pmax[pi] = bvv; pcol[pi] = bcc; psum[pi] = sp;
        pnmax[pi] = -mnv; pnsum[pi] = sn;
      }
    }
  }

  // ---- per-column tile max ----
#pragma unroll
  for (int ct = 0; ct < 4; ++ct){
    float cm = -1e30f;
#pragma unroll
    for (int rt=0; rt<2; ++rt)
#pragma unroll
      for (int reg=0; reg<4; ++reg) cm = fmaxf(cm, acc[rt][ct][reg]);
    cm = fmaxf(cm, __shfl_xor(cm, 16));
    cm = fmaxf(cm, __shfl_xor(cm, 32));
    if (l4 == 0)
      pcolmax[(size_t)(rb*2 + (w>>1))*M_SLOTS + colBase + wc + ct*16 + l15] = cm;
  }

  // ---- S bf16 write (staged through LDS for coalescing) ----
  __syncthreads();
  unsigned short* Sout = (unsigned short*)smem;  // [64][136]
#pragma unroll
  for (int rt=0; rt<2; ++rt)
#pragma unroll
    for (int ct=0; ct<4; ++ct)
#pragma unroll
      for (int reg=0; reg<4; ++reg)
        Sout[(wr + rt*16 + l4*4 + reg)*136 + wc + ct*16 + l15] = bf16_rne(acc[rt][ct][reg]);
  __syncthreads();
#pragma unroll
  for (int p = 0; p < 4; ++p){
    int row = (t >> 4) + p*16;
    int c8 = (t & 15) * 8;
    uint4 v = *(uint4*)&Sout[row*136 + c8];
    *(uint4*)&Sb[(size_t)(rowBase+row)*M_SLOTS + colBase + c8] = v;
  }
}

__global__ __launch_bounds__(256) void merge_rows(
    const float* __restrict__ pmax, const int* __restrict__ pcol,
    const float* __restrict__ psum, const float* __restrict__ pnmax,
    const float* __restrict__ pnsum,
    float* __restrict__ rowm, float* __restrict__ rsp,
    float* __restrict__ rmn, float* __restrict__ rsn, int* __restrict__ gidx)
{
  int row = blockIdx.x*256 + threadIdx.x;
  const size_t base = (size_t)row*32;
  float m = -1e30f; int g = 0;
  for (int i=0;i<32;++i){
    float v = pmax[base+i];
    if (v > m){ m = v; g = pcol[base+i]; }
  }
  float s = 0.f;
  for (int i=0;i<32;++i) s += psum[base+i] * __expf(pmax[base+i]-m);
  float mn = -1e30f;
  for (int i=0;i<32;++i) mn = fmaxf(mn, pnmax[base+i]);
  float sn = 0.f;
  for (int i=0;i<32;++i) sn += pnsum[base+i] * __expf(pnmax[base+i]-mn);
  rowm[row]=m; gidx[row]=g; rsp[row]=1.f/s; rmn[row]=mn; rsn[row]=1.f/sn;
}

__global__ __launch_bounds__(256) void merge_cols(const float* __restrict__ pcolmax,
                                                  float* __restrict__ colmax)
{
  int c = blockIdx.x*256 + threadIdx.x;
  float m = -1e30f;
  for (int r=0;r<512;++r) m = fmaxf(m, pcolmax[(size_t)r*M_SLOTS + c]);
  colmax[c] = m;
}

// P = smP @ K, Pn = smN @ K; weights built on the fly from bf16 S; outputs gated by Q.
// Tile: BM=64 rows x BN=128 h-cols, BK=64 slots. Wave w owns rows w*16..+16, all 8 col-tiles.
__global__ __launch_bounds__(256) void pv_mfma(
    const unsigned short* __restrict__ Sb, const unsigned short* __restrict__ Kt,
    const float* __restrict__ rowm, const float* __restrict__ rsp,
    const float* __restrict__ rmn, const float* __restrict__ rsn,
    const float* __restrict__ Q,
    float* __restrict__ outP, float* __restrict__ outN)
{
  __shared__ char smem[34048];
  unsigned short* Bt = (unsigned short*)smem;   // [128 h][64 slots] bf16, chunk-swizzled
  const int t = threadIdx.x, lane = t & 63, w = t >> 6;
  const int l15 = lane & 15, l4 = lane >> 4;
  const int rowBase = blockIdx.x * 64;
  const int hBase = blockIdx.y * 128;
  const int arow = rowBase + w*16 + l15;
  const float mp = rowm[arow], mn = rmn[arow];

  f32x4 accP[8], accN[8];
#pragma unroll
  for (int i=0;i<8;++i){
    accP[i] = (f32x4){0.f,0.f,0.f,0.f};
    accN[i] = (f32x4){0.f,0.f,0.f,0.f};
  }

  for (int kt = 0; kt < 32; ++kt){
    const int k0 = kt*64;
#pragma unroll
    for (int p=0;p<4;++p){
      int idx = p*256 + t;
      int r = idx >> 3, c = idx & 7;
      int cc = c ^ (r & 7);
      size_t go = (size_t)(hBase + r)*M_SLOTS + k0 + cc*8;
      glds16(Kt + go, (char*)Bt + idx*16);
    }
    // A-side: read 64 bf16 S values for this lane's row, build exp weights
    short8v ap[2], an[2];
#pragma unroll
    for (int s=0;s<2;++s){
      short8v sv = *(const short8v*)&Sb[(size_t)arow*M_SLOTS + k0 + s*32 + l4*8];
#pragma unroll
      for (int e=0;e<8;++e){
        float sval = bf16_to_f32((unsigned short)sv[e]);
        ap[s][e] = (short)bf16_rne(__expf(sval - mp));
        an[s][e] = (short)bf16_rne(__expf(-sval - mn));
      }
    }
    __syncthreads();
#pragma unroll
    for (int s=0;s<2;++s){
#pragma unroll
      for (int ct=0; ct<8; ++ct){
        int r = ct*16 + l15;
        short8v b = *(const short8v*)((const char*)Bt + r*128 + ((s*4 + l4) ^ (r & 7))*16);
        accP[ct] = __builtin_amdgcn_mfma_f32_16x16x32_bf16(ap[s], b, accP[ct], 0,0,0);
        accN[ct] = __builtin_amdgcn_mfma_f32_16x16x32_bf16(an[s], b, accN[ct], 0,0,0);
      }
    }
    __syncthreads();
  }

  // epilogue: scale by 1/rowsum, gate by Q, write (P then N, staged via LDS)
  const int crow = w*16 + l4*4;
  float ispr[4], isnr[4];
#pragma unroll
  for (int reg=0;reg<4;++reg){
    ispr[reg] = rsp[rowBase + crow + reg];
    isnr[reg] = rsn[rowBase + crow + reg];
  }
  float* Pout = (float*)smem;  // [64][132]
#pragma unroll
  for (int ct=0; ct<8; ++ct)
#pragma unroll
    for (int reg=0; reg<4; ++reg)
      Pout[(crow + reg)*132 + ct*16 + l15] = accP[ct][reg] * ispr[reg];
  __syncthreads();
#pragma unroll
  for (int p=0;p<8;++p){
    int row = (t>>5) + p*8;
    int c4 = (t&31)*4;
    float4 pv = *(float4*)&Pout[row*132 + c4];
    float4 qv = *(const float4*)&Q[(size_t)(rowBase+row)*HID + hBase + c4];
    float4 o; o.x=pv.x*qv.x; o.y=pv.y*qv.y; o.z=pv.z*qv.z; o.w=pv.w*qv.w;
    *(float4*)&outP[(size_t)(rowBase+row)*HID + hBase + c4] = o;
  }
  __syncthreads();
#pragma unroll
  for (int ct=0; ct<8; ++ct)
#pragma unroll
    for (int reg=0; reg<4; ++reg)
      Pout[(crow + reg)*132 + ct*16 + l15] = accN[ct][reg] * isnr[reg];
  __syncthreads();
#pragma unroll
  for (int p=0;p<8;++p){
    int row = (t>>5) + p*8;
    int c4 = (t&31)*4;
    float4 pv = *(float4*)&Pout[row*132 + c4];
    float4 qv = *(const float4*)&Q[(size_t)(rowBase+row)*HID + hBase + c4];
    float4 o; o.x=pv.x*qv.x; o.y=pv.y*qv.y; o.z=pv.z*qv.z; o.w=pv.w*qv.w;
    *(float4*)&outN[(size_t)(rowBase+row)*HID + hBase + c4] = o;
  }
}

// One block per memory slot m (float colmax version).
__global__ __launch_bounds__(256) void upload2(const float* __restrict__ Q,
                                               const float* __restrict__ Km,
                                               const float* __restrict__ rowm,
                                               const int* __restrict__ gidx,
                                               const float* __restrict__ colmax,
                                               const int* __restrict__ train,
                                               float* __restrict__ mem)
{
  const int m = blockIdx.x, t = threadIdx.x;
  const int h0 = t * 2;
  float2 kv = *(const float2*)&Km[(size_t)m*HID + h0];
  if (*train == 0){
    mem[(size_t)m*HID + h0]     = kv.x;
    mem[(size_t)m*HID + h0 + 1] = kv.y;
    return;
  }
  const float cmax = colmax[m];
  float a0 = 0.f, a1 = 0.f;
  __shared__ int cnt;
  __shared__ int   lidx[256];
  __shared__ float lw[256];
  for (int base = 0; base < N_ROWS; base += 256){
    if (t == 0) cnt = 0;
    __syncthreads();
    int i = base + t;
    if (gidx[i] == m){
      int p = atomicAdd(&cnt, 1);
      lidx[p] = i;
      lw[p]   = __expf(rowm[i] - cmax);
    }
    __syncthreads();
    int c = cnt;
    for (int k = 0; k < c; ++k){
      float wv = lw[k];
      const float* q = &Q[(size_t)lidx[k]*HID + h0];
      a0 += wv * q[0];
      a1 += wv * q[1];
    }
    __syncthreads();
  }
  float v0 = a0 + kv.x, v1 = a1 + kv.y;
  __shared__ float red[256];
  red[t] = v0*v0 + v1*v1;
  __syncthreads();
  for (int s = 128; s > 0; s >>= 1){
    if (t < s) red[t] += red[t + s];
    __syncthreads();
  }
  float nrm = sqrtf(red[0]);
  float rinv = 1.f / fmaxf(nrm, 1e-12f);
  mem[(size_t)m*HID + h0]     = v0 * rinv;
  mem[(size_t)m*HID + h0 + 1] = v1 * rinv;
}

// ============================ fallback path (round-1, proven) ============================

__global__ __launch_bounds__(256) void stats_kernel(const float* __restrict__ Q,
                                                    const float* __restrict__ Km,
                                                    float* __restrict__ rowm, float* __restrict__ rsp,
                                                    float* __restrict__ rmn,  float* __restrict__ rsn,
                                                    int* __restrict__ gidx,   unsigned* __restrict__ colmaxU)
{
  __shared__ float Ks[16][516];
  __shared__ float Ss[16][17];
  const int t  = threadIdx.x;
  const int rA = t >> 4, cA = t & 15;
  const int bR = blockIdx.x * 16;
  const float* qrow = Q + (size_t)(bR + rA) * HID;

  float m_run = -INFINITY, s_run = 0.f;
  float mn_run = -INFINITY, sn_run = 0.f;
  float bv = -INFINITY; int bj = 0;

  for (int mt = 0; mt < M_SLOTS/16; ++mt){
#pragma unroll
    for (int p = 0; p < 8; ++p){
      int fi = (p*256 + t) * 4;
      int c = fi >> 9, k = fi & 511;
      *(float4*)&Ks[c][k] = *(const float4*)&Km[(size_t)(mt*16 + c)*HID + k];
    }
    __syncthreads();

    float acc = 0.f;
#pragma unroll 8
    for (int k = 0; k < HID; k += 4){
      float4 q4 = *(const float4*)&qrow[k];
      float4 k4 = *(const float4*)&Ks[cA][k];
      acc += q4.x*k4.x + q4.y*k4.y + q4.z*k4.z + q4.w*k4.w;
    }

    float tv = acc; int tj = mt*16 + cA; float tmin = acc;
#pragma unroll
    for (int d = 1; d < 16; d <<= 1){
      float ov = __shfl_xor(tv, d);
      int   oj = __shfl_xor(tj, d);
      float om = __shfl_xor(tmin, d);
      if (ov > tv || (ov == tv && oj < tj)){ tv = ov; tj = oj; }
      tmin = fminf(tmin, om);
    }
    float sp = __expf(acc - tv);
    float sn = __expf(tmin - acc);
#pragma unroll
    for (int d = 1; d < 16; d <<= 1){
      sp += __shfl_xor(sp, d);
      sn += __shfl_xor(sn, d);
    }
    {
      float nm = fmaxf(m_run, tv);
      s_run = s_run * __expf(m_run - nm) + sp * __expf(tv - nm);
      m_run = nm;
      float tmn = -tmin;
      float nmn = fmaxf(mn_run, tmn);
      sn_run = sn_run * __expf(mn_run - nmn) + sn * __expf(tmn - nmn);
      mn_run = nmn;
      if (tv > bv){ bv = tv; bj = tj; }
    }
    Ss[rA][cA] = acc;
    __syncthreads();
    if (t < 16){
      float cm = Ss[0][t];
#pragma unroll
      for (int r = 1; r < 16; ++r) cm = fmaxf(cm, Ss[r][t]);
      atomicMax(&colmaxU[mt*16 + t], fmap(cm));
    }
    __syncthreads();
  }
  if (cA == 0){
    int row = bR + rA;
    rowm[row] = m_run;
    rsp[row]  = 1.f / s_run;
    rmn[row]  = mn_run;
    rsn[row]  = 1.f / sn_run;
    gidx[row] = bj;
  }
}

__global__ __launch_bounds__(256) void pv_kernel(const float* __restrict__ Q,
                                                 const float* __restrict__ Km,
                                                 const float* __restrict__ rowm, const float* __restrict__ rsp,
                                                 const float* __restrict__ rmn,  const float* __restrict__ rsn,
                                                 float* __restrict__ outP, float* __restrict__ outN)
{
  __shared__ float Ks[16][516];
  __shared__ float Wpc[16][20];
  __shared__ float Wnc[16][20];
  const int t  = threadIdx.x;
  const int rA = t >> 4, cA = t & 15;
  const int bR = blockIdx.x * 16;
  const int w  = t >> 6, lane = t & 63;
  const int r0 = w * 4;
  const int h0 = lane * 8;
  const float* qrow = Q + (size_t)(bR + rA) * HID;
  const float mp = rowm[bR + rA], isp = rsp[bR + rA];
  const float mn = rmn[bR + rA],  isn = rsn[bR + rA];

  float accp[4][8] = {};
  float accn[4][8] = {};

  for (int mt = 0; mt < M_SLOTS/16; ++mt){
#pragma unroll
    for (int p = 0; p < 8; ++p){
      int fi = (p*256 + t) * 4;
      int c = fi >> 9, k = fi & 511;
      *(float4*)&Ks[c][k] = *(const float4*)&Km[(size_t)(mt*16 + c)*HID + k];
    }
    __syncthreads();

    float s = 0.f;
#pragma unroll 8
    for (int k = 0; k < HID; k += 4){
      float4 q4 = *(const float4*)&qrow[k];
      float4 k4 = *(const float4*)&Ks[cA][k];
      s += q4.x*k4.x + q4.y*k4.y + q4.z*k4.z + q4.w*k4.w;
    }
    Wpc[cA][rA] = __expf(s - mp) * isp;
    Wnc[cA][rA] = __expf(-s - mn) * isn;
    __syncthreads();

#pragma unroll
    for (int c = 0; c < 16; ++c){
      float4 kv0 = *(const float4*)&Ks[c][h0];
      float4 kv1 = *(const float4*)&Ks[c][h0 + 4];
      float4 wp4 = *(const float4*)&Wpc[c][r0];
      float4 wn4 = *(const float4*)&Wnc[c][r0];
      float wp[4] = {wp4.x, wp4.y, wp4.z, wp4.w};
      float wn[4] = {wn4.x, wn4.y, wn4.z, wn4.w};
#pragma unroll
      for (int r = 0; r < 4; ++r){
        accp[r][0] += wp[r]*kv0.x; accp[r][1] += wp[r]*kv0.y;
        accp[r][2] += wp[r]*kv0.z; accp[r][3] += wp[r]*kv0.w;
        accp[r][4] += wp[r]*kv1.x; accp[r][5] += wp[r]*kv1.y;
        accp[r][6] += wp[r]*kv1.z; accp[r][7] += wp[r]*kv1.w;
        accn[r][0] += wn[r]*kv0.x; accn[r][1] += wn[r]*kv0.y;
        accn[r][2] += wn[r]*kv0.z; accn[r][3] += wn[r]*kv0.w;
        accn[r][4] += wn[r]*kv1.x; accn[r][5] += wn[r]*kv1.y;
        accn[r][6] += wn[r]*kv1.z; accn[r][7] += wn[r]*kv1.w;
      }
    }
    __syncthreads();
  }

#pragma unroll
  for (int r = 0; r < 4; ++r){
    size_t row = (size_t)(bR + r0 + r);
    const float* q = &Q[row*HID + h0];
    float4 q0 = *(const float4*)&q[0];
    float4 q1 = *(const float4*)&q[4];
    float4 o0, o1;
    o0.x = q0.x*accp[r][0]; o0.y = q0.y*accp[r][1]; o0.z = q0.z*accp[r][2]; o0.w = q0.w*accp[r][3];
    o1.x = q1.x*accp[r][4]; o1.y = q1.y*accp[r][5]; o1.z = q1.z*accp[r][6]; o1.w = q1.w*accp[r][7];
    *(float4*)&outP[row*HID + h0]     = o0;
    *(float4*)&outP[row*HID + h0 + 4] = o1;
    o0.x = q0.x*accn[r][0]; o0.y = q0.y*accn[r][1]; o0.z = q0.z*accn[r][2]; o0.w = q0.w*accn[r][3];
    o1.x = q1.x*accn[r][4]; o1.y = q1.y*accn[r][5]; o1.z = q1.z*accn[r][6]; o1.w = q1.w*accn[r][7];
    *(float4*)&outN[row*HID + h0]     = o0;
    *(float4*)&outN[row*HID + h0 + 4] = o1;
  }
}

__global__ __launch_bounds__(256) void upload_kernel(const float* __restrict__ Q,
                                                     const float* __restrict__ Km,
                                                     const float* __restrict__ rowm,
                                                     const int* __restrict__ gidx,
                                                     const unsigned* __restrict__ colmaxU,
                                                     const int* __restrict__ train,
                                                     float* __restrict__ mem)
{
  const int m = blockIdx.x, t = threadIdx.x;
  const int h0 = t * 2;
  float2 kv = *(const float2*)&Km[(size_t)m*HID + h0];
  if (*train == 0){
    mem[(size_t)m*HID + h0]     = kv.x;
    mem[(size_t)m*HID + h0 + 1] = kv.y;
    return;
  }
  const float cmax = funmap(colmaxU[m]);
  float a0 = 0.f, a1 = 0.f;
  __shared__ int cnt;
  __shared__ int   lidx[256];
  __shared__ float lw[256];
  for (int base = 0; base < N_ROWS; base += 256){
    if (t == 0) cnt = 0;
    __syncthreads();
    int i = base + t;
    if (gidx[i] == m){
      int p = atomicAdd(&cnt, 1);
      lidx[p] = i;
      lw[p]   = __expf(rowm[i] - cmax);
    }
    __syncthreads();
    int c = cnt;
    for (int k = 0; k < c; ++k){
      float wv = lw[k];
      const float* q = &Q[(size_t)lidx[k]*HID + h0];
      a0 += wv * q[0];
      a1 += wv * q[1];
    }
    __syncthreads();
  }
  float v0 = a0 + kv.x, v1 = a1 + kv.y;
  __shared__ float red[256];
  red[t] = v0*v0 + v1*v1;
  __syncthreads();
  for (int s = 128; s > 0; s >>= 1){
    if (t < s) red[t] += red[t + s];
    __syncthreads();
  }
  float nrm = sqrtf(red[0]);
  float rinv = 1.f / fmaxf(nrm, 1e-12f);
  mem[(size_t)m*HID + h0]     = v0 * rinv;
  mem[(size_t)m*HID + h0 + 1] = v1 * rinv;
}

// ============================ host ============================

extern "C" void kernel_launch(void* const* d_in, const int* in_sizes, int n_in,
                              void* d_out, int out_size, void* d_ws, size_t ws_size,
                              hipStream_t stream)
{
  const float* x   = (const float*)d_in[0];
  const float* Km  = (const float*)d_in[1];
  const float* W1  = (const float*)d_in[2];
  const float* b1  = (const float*)d_in[3];
  const float* W2  = (const float*)d_in[4];
  const float* b2  = (const float*)d_in[5];
  const float* W3  = (const float*)d_in[6];
  const float* b3  = (const float*)d_in[7];
  const float* Wd  = (const float*)d_in[8];
  const float* bd  = (const float*)d_in[9];
  const int* train = (const int*)d_in[10];

  float* out  = (float*)d_out;
  float* pred = out;
  float* outN = out + 16384;
  float* outP = out + 16384 + 8388608;
  float* memo = out + 16384 + 2*8388608;

  char* ws = (char*)d_ws;
  // common
  float* Q = (float*)ws;                                     //  33,554,432
  // MFMA-path layout
  unsigned short* Qhi   = (unsigned short*)(ws +  33554432); //  16,777,216
  unsigned short* Qlo   = (unsigned short*)(ws +  50331648); //  16,777,216
  unsigned short* Sb    = (unsigned short*)(ws +  67108864); //  67,108,864
  unsigned short* Khi   = (unsigned short*)(ws + 134217728); //   2,097,152
  unsigned short* Klo   = (unsigned short*)(ws + 136314880); //   2,097,152
  unsigned short* Kt    = (unsigned short*)(ws + 138412032); //   2,097,152
  float*    pmax    = (float*)(ws + 140509184);              //   2,097,152
  int*      pcol    = (int*)  (ws + 142606336);              //   2,097,152
  float*    psum    = (float*)(ws + 144703488);              //   2,097,152
  float*    pnmax   = (float*)(ws + 146800640);              //   2,097,152
  float*    pnsum   = (float*)(ws + 148897792);              //   2,097,152
  float*    pcolmax = (float*)(ws + 150994944);              //   4,194,304
  float*    rowm    = (float*)(ws + 155189248);
  float*    rsp     = (float*)(ws + 155254784);
  float*    rmn     = (float*)(ws + 155320320);
  float*    rsn     = (float*)(ws + 155385856);
  int*      gidx    = (int*)  (ws + 155451392);
  float*    colmax  = (float*)(ws + 155516928);
  const size_t NEED = 155582464ull;

  float* h1 = outN;   // dead until PV overwrites
  float* h2 = outP;

  dim3 blk(256);
  gemm_relu<<<dim3(HID/64, N_ROWS/64), blk, 0, stream>>>(x,  W1, b1, h1, N_ROWS, D_INN, HID);
  gemm_relu<<<dim3(HID/64, N_ROWS/64), blk, 0, stream>>>(h1, W2, b2, h2, N_ROWS, HID,  HID);
  gemm_relu<<<dim3(HID/64, N_ROWS/64), blk, 0, stream>>>(h2, W3, b3, Q,  N_ROWS, HID,  HID);

  if (ws_size >= NEED){
    cvt_split<<<4096, blk, 0, stream>>>(Q,  Qhi, Qlo, N_ROWS*HID);
    cvt_split<<<512,  blk, 0, stream>>>(Km, Khi, Klo, M_SLOTS*HID);
    kt_kernel<<<dim3(32, 8), blk, 0, stream>>>(Km, Kt);
    sgemm_stats<<<dim3(256, 16), blk, 0, stream>>>(Qhi, Qlo, Khi, Klo, Sb,
                                                   pmax, pcol, psum, pnmax, pnsum, pcolmax);
    merge_rows<<<64, blk, 0, stream>>>(pmax, pcol, psum, pnmax, pnsum,
                                       rowm, rsp, rmn, rsn, gidx);
    merge_cols<<<8, blk, 0, stream>>>(pcolmax, colmax);
    pv_mfma<<<dim3(256, 4), blk, 0, stream>>>(Sb, Kt, rowm, rsp, rmn, rsn, Q, outP, outN);
    upload2<<<M_SLOTS, blk, 0, stream>>>(Q, Km, rowm, gidx, colmax, train, memo);
  } else {
    // fallback: round-1 proven path (needs only ~34 MB of ws)
    float*    f_rowm    = (float*)(ws + 33554432);
    float*    f_rsp     = (float*)(ws + 33619968);
    float*    f_rmn     = (float*)(ws + 33685504);
    float*    f_rsn     = (float*)(ws + 33751040);
    int*      f_gidx    = (int*)  (ws + 33816576);
    unsigned* f_colmaxU = (unsigned*)(ws + 33882112);
    hipMemsetAsync(f_colmaxU, 0, M_SLOTS*sizeof(unsigned), stream);
    stats_kernel<<<N_ROWS/16, blk, 0, stream>>>(Q, Km, f_rowm, f_rsp, f_rmn, f_rsn, f_gidx, f_colmaxU);
    pv_kernel  <<<N_ROWS/16, blk, 0, stream>>>(Q, Km, f_rowm, f_rsp, f_rmn, f_rsn, outP, outN);
    upload_kernel<<<M_SLOTS, blk, 0, stream>>>(Q, Km, f_rowm, f_gidx, f_colmaxU, train, memo);
  }
  pred_kernel<<<N_ROWS/4, blk, 0, stream>>>(Q, Wd, bd, pred);
}